// Round 1
// baseline (817.335 us; speedup 1.0000x reference)
//
#include <hip/hip_runtime.h>
#include <math.h>

typedef __bf16 bf16_t;
typedef bf16_t bf16x8 __attribute__((ext_vector_type(8)));
typedef bf16_t bf16x4 __attribute__((ext_vector_type(4)));
typedef float  f32x4  __attribute__((ext_vector_type(4)));
typedef short  s16x8  __attribute__((ext_vector_type(8)));

#define T_TOK 8192
#define DM 1024
#define DF 4096
#define NE 8
#define NP 16384  // total token-expert pairs = T_TOK * 2

// ---- single switch point for MFMA operand typing ----
__device__ __forceinline__ f32x4 mfma_bf16(bf16x8 a, bf16x8 b, f32x4 c) {
  return __builtin_amdgcn_mfma_f32_16x16x32_bf16(a, b, c, 0, 0, 0);
}

__device__ __forceinline__ void gload16(const void* g, void* l) {
  __builtin_amdgcn_global_load_lds((const __attribute__((address_space(1))) void*)g,
                                   (__attribute__((address_space(3))) void*)l, 16, 0, 0);
}

// meta layout (ints): [0..7]=cnt1 (top-1 counts) [8..15]=cnt2 (pair counts)
// [16..23]=cursor [24..31]=off [32..39]=probsum(float) [40]=zsum(float)

// ============================ router ============================
__global__ __launch_bounds__(256) void k_router(
    const float* __restrict__ x, const float* __restrict__ gate_w,
    const float* __restrict__ ln_g, const float* __restrict__ ln_b,
    float* __restrict__ out, bf16_t* __restrict__ xn,
    int* __restrict__ eidx, float* __restrict__ gts, int* __restrict__ meta)
{
  int* cnt1 = meta;
  int* cnt2 = meta + 8;
  float* probsum = (float*)(meta + 32);
  float* zsum    = (float*)(meta + 40);

  __shared__ float sprob[8];
  __shared__ float sz;
  __shared__ int sc1[8], sc2[8];
  if (threadIdx.x < 8) { sprob[threadIdx.x] = 0.f; sc1[threadIdx.x] = 0; sc2[threadIdx.x] = 0; }
  if (threadIdx.x == 8) sz = 0.f;
  __syncthreads();

  int lane = threadIdx.x & 63, wv = threadIdx.x >> 6;
  int t = blockIdx.x * 4 + wv;
  const float* xt = x + (size_t)t * DM;

  float4 v[4];
  float s1 = 0.f, s2 = 0.f;
  #pragma unroll
  for (int c = 0; c < 4; ++c) {
    v[c] = *(const float4*)(xt + c * 256 + lane * 4);
    s1 += v[c].x + v[c].y + v[c].z + v[c].w;
    s2 += v[c].x * v[c].x + v[c].y * v[c].y + v[c].z * v[c].z + v[c].w * v[c].w;
  }
  #pragma unroll
  for (int o = 32; o > 0; o >>= 1) { s1 += __shfl_xor(s1, o, 64); s2 += __shfl_xor(s2, o, 64); }
  float mu = s1 * (1.f / DM);
  float var = s2 * (1.f / DM) - mu * mu;
  float rstd = rsqrtf(var + 1e-5f);

  float xv[16];
  #pragma unroll
  for (int c = 0; c < 4; ++c) {
    int d = c * 256 + lane * 4;
    float4 g4 = *(const float4*)(ln_g + d);
    float4 b4 = *(const float4*)(ln_b + d);
    xv[c*4+0] = (v[c].x - mu) * rstd * g4.x + b4.x;
    xv[c*4+1] = (v[c].y - mu) * rstd * g4.y + b4.y;
    xv[c*4+2] = (v[c].z - mu) * rstd * g4.z + b4.z;
    xv[c*4+3] = (v[c].w - mu) * rstd * g4.w + b4.w;
    *(float4*)(out + (size_t)t * DM + d) = v[c];  // out starts as residual x
    bf16x4 pk = { (bf16_t)xv[c*4+0], (bf16_t)xv[c*4+1], (bf16_t)xv[c*4+2], (bf16_t)xv[c*4+3] };
    *(bf16x4*)(xn + (size_t)t * DM + d) = pk;
  }

  float lg[8];
  #pragma unroll
  for (int e = 0; e < 8; ++e) {
    float p = 0.f;
    #pragma unroll
    for (int c = 0; c < 4; ++c) {
      int d = c * 256 + lane * 4;
      float4 g4 = *(const float4*)(gate_w + e * DM + d);
      p += xv[c*4+0] * g4.x + xv[c*4+1] * g4.y + xv[c*4+2] * g4.z + xv[c*4+3] * g4.w;
    }
    #pragma unroll
    for (int o = 32; o > 0; o >>= 1) p += __shfl_xor(p, o, 64);
    lg[e] = p;
  }

  if (lane == 0) {
    float m = -1e30f;
    #pragma unroll
    for (int e = 0; e < 8; ++e) { lg[e] = fminf(fmaxf(lg[e], -10.f), 10.f); m = fmaxf(m, lg[e]); }
    float pr[8]; float se = 0.f;
    #pragma unroll
    for (int e = 0; e < 8; ++e) { pr[e] = expf(lg[e] - m); se += pr[e]; }
    float inv = 1.f / se;
    #pragma unroll
    for (int e = 0; e < 8; ++e) pr[e] *= inv;
    float lse = m + logf(se);

    int e0 = 0; float p0 = pr[0];
    #pragma unroll
    for (int e = 1; e < 8; ++e) if (pr[e] > p0) { p0 = pr[e]; e0 = e; }
    int e1 = -1; float p1 = -1.f;
    #pragma unroll
    for (int e = 0; e < 8; ++e) if (e != e0 && pr[e] > p1) { p1 = pr[e]; e1 = e; }
    float s = p0 + p1 + 1e-8f;
    eidx[t*2]   = e0; eidx[t*2+1] = e1;
    gts[t*2]    = p0 / s; gts[t*2+1] = p1 / s;

    atomicAdd(&sc1[e0], 1);
    atomicAdd(&sc2[e0], 1);
    atomicAdd(&sc2[e1], 1);
    #pragma unroll
    for (int e = 0; e < 8; ++e) atomicAdd(&sprob[e], pr[e]);
    atomicAdd(&sz, lse * lse);
  }
  __syncthreads();
  if (threadIdx.x < 8) {
    if (sc1[threadIdx.x]) atomicAdd(&cnt1[threadIdx.x], sc1[threadIdx.x]);
    if (sc2[threadIdx.x]) atomicAdd(&cnt2[threadIdx.x], sc2[threadIdx.x]);
    atomicAdd(&probsum[threadIdx.x], sprob[threadIdx.x]);
  }
  if (threadIdx.x == 8) atomicAdd(zsum, sz);
}

// ================= weight convert + transpose (fp32 [R][C] -> bf16 [C][R]) =================
__global__ __launch_bounds__(256) void k_convT(
    const float* __restrict__ src, bf16_t* __restrict__ dst, int R, int C)
{
  __shared__ float tile[32][33];
  int e = blockIdx.z;
  const float* s = src + (size_t)e * R * C;
  bf16_t* d = dst + (size_t)e * R * C;
  int c0 = blockIdx.x * 32, r0 = blockIdx.y * 32;
  int tx = threadIdx.x, ty = threadIdx.y;
  #pragma unroll
  for (int i = 0; i < 4; ++i) {
    int r = ty + i * 8;
    tile[r][tx] = s[(size_t)(r0 + r) * C + c0 + tx];
  }
  __syncthreads();
  #pragma unroll
  for (int i = 0; i < 4; ++i) {
    int cc = ty + i * 8;
    d[(size_t)(c0 + cc) * R + r0 + tx] = (bf16_t)tile[tx][cc];
  }
}

// ============================ tiny serial kernels ============================
__global__ void k_offsets(int* meta) {
  if (threadIdx.x == 0 && blockIdx.x == 0) {
    int acc = 0;
    for (int e = 0; e < 8; ++e) { meta[24 + e] = acc; acc += meta[8 + e]; }
  }
}

__global__ __launch_bounds__(256) void k_assign(
    const int* __restrict__ eidx, const float* __restrict__ gts,
    int* __restrict__ meta, int* __restrict__ list, float* __restrict__ gl)
{
  int t = blockIdx.x * 256 + threadIdx.x;
  int* cursor = meta + 16;
  const int* off = meta + 24;
  #pragma unroll
  for (int k = 0; k < 2; ++k) {
    int e = eidx[t*2 + k];
    int pos = atomicAdd(&cursor[e], 1);
    int slot = off[e] + pos;
    list[slot] = t;
    gl[slot] = gts[t*2 + k];
  }
}

__global__ void k_aux(const int* __restrict__ meta, float* __restrict__ aux_out) {
  if (threadIdx.x == 0 && blockIdx.x == 0) {
    const int* cnt1 = meta;
    const float* probsum = (const float*)(meta + 32);
    const float* zsum    = (const float*)(meta + 40);
    float s = 0.f;
    for (int e = 0; e < 8; ++e)
      s += ((float)cnt1[e] * (1.f / 8192.f)) * (probsum[e] * (1.f / 8192.f));
    aux_out[0] = 8.f * s * 0.01f + (zsum[0] * (1.f / 8192.f)) * 0.001f;
  }
}

// ============================ grouped GEMM 1: H = gelu(Xn @ W1 + b1) ============================
// grid: (DF/128, 64, NE), block 256. A rows gathered via list. C/D: col=lane&15, row=(lane>>4)*4+reg.
__global__ __launch_bounds__(256) void k_ffn1(
    const bf16_t* __restrict__ xn, const bf16_t* __restrict__ w1t,
    const float* __restrict__ b1, bf16_t* __restrict__ H,
    const int* __restrict__ list, const int* __restrict__ meta)
{
  int e = blockIdx.z;
  int cnt = meta[8 + e];
  int m0 = blockIdx.y * 128;
  if (m0 >= cnt) return;
  int offe = meta[24 + e];
  int n0 = blockIdx.x * 128;

  __shared__ __align__(1024) char smem[16384];
  int tid = threadIdx.x, lane = tid & 63, wv = tid >> 6;

  const bf16_t* srcA[2]; const bf16_t* srcB[2];
  unsigned ldso[2];
  #pragma unroll
  for (int r = 0; r < 2; ++r) {
    int o = r * 4096 + tid * 16;
    int row = o >> 6;
    int ch = ((o >> 4) & 3) ^ (row & 3);          // pre-swizzled global source chunk
    int mrow = min(m0 + row, cnt - 1);
    int token = list[offe + mrow];
    srcA[r] = xn + (size_t)token * DM + ch * 8;
    srcB[r] = w1t + ((size_t)e * DF + n0 + row) * DM + ch * 8;
    ldso[r] = (unsigned)(r * 4096 + wv * 1024);    // wave-uniform LDS base
  }

  int fr = (wv >> 1) * 64 + (lane & 15);
  int fc = (wv & 1) * 64 + (lane & 15);
  int kqB = (lane >> 4) * 16;
  unsigned a_off[4], b_off[4];
  #pragma unroll
  for (int i = 0; i < 4; ++i) {
    int ra = fr + i * 16, rb = fc + i * 16;
    a_off[i] = (unsigned)((ra * 64 + kqB) ^ ((ra & 3) << 4));
    b_off[i] = (unsigned)(8192 + ((rb * 64 + kqB) ^ ((rb & 3) << 4)));
  }

  f32x4 acc[4][4];
  #pragma unroll
  for (int i = 0; i < 4; ++i)
    #pragma unroll
    for (int j = 0; j < 4; ++j)
      acc[i][j] = (f32x4){0.f, 0.f, 0.f, 0.f};

  for (int kt = 0; kt < DM / 32; ++kt) {
    #pragma unroll
    for (int r = 0; r < 2; ++r) {
      gload16(srcA[r] + kt * 32, smem + ldso[r]);
      gload16(srcB[r] + kt * 32, smem + 8192 + ldso[r]);
    }
    __syncthreads();
    bf16x8 af[4], bfr[4];
    #pragma unroll
    for (int i = 0; i < 4; ++i) af[i]  = *(const bf16x8*)(smem + a_off[i]);
    #pragma unroll
    for (int i = 0; i < 4; ++i) bfr[i] = *(const bf16x8*)(smem + b_off[i]);
    #pragma unroll
    for (int i = 0; i < 4; ++i)
      #pragma unroll
      for (int j = 0; j < 4; ++j)
        acc[i][j] = mfma_bf16(af[i], bfr[j], acc[i][j]);
    __syncthreads();
  }

  int rbase = (wv >> 1) * 64 + ((lane >> 4) << 2);
  int cbase = n0 + (wv & 1) * 64 + (lane & 15);
  #pragma unroll
  for (int i = 0; i < 4; ++i) {
    #pragma unroll
    for (int q = 0; q < 4; ++q) {
      int mg = m0 + rbase + i * 16 + q;
      if (mg < cnt) {
        size_t hrow = (size_t)(offe + mg) * DF;
        #pragma unroll
        for (int j = 0; j < 4; ++j) {
          int col = cbase + j * 16;
          float hv = acc[i][j][q] + b1[e * DF + col];
          hv = 0.5f * hv * (1.f + erff(hv * 0.70710678118f));
          H[hrow + col] = (bf16_t)hv;
        }
      }
    }
  }
}

// ============================ grouped GEMM 2: out += g * (H @ W2 + b2) ============================
// grid: (DM/128, 64, NE), block 256.
__global__ __launch_bounds__(256) void k_ffn2(
    const bf16_t* __restrict__ H, const bf16_t* __restrict__ w2t,
    const float* __restrict__ b2, float* __restrict__ out,
    const int* __restrict__ list, const float* __restrict__ gl,
    const int* __restrict__ meta)
{
  int e = blockIdx.z;
  int cnt = meta[8 + e];
  int m0 = blockIdx.y * 128;
  if (m0 >= cnt) return;
  int offe = meta[24 + e];
  int n0 = blockIdx.x * 128;

  __shared__ __align__(1024) char smem[16384];
  int tid = threadIdx.x, lane = tid & 63, wv = tid >> 6;

  const bf16_t* srcA[2]; const bf16_t* srcB[2];
  unsigned ldso[2];
  #pragma unroll
  for (int r = 0; r < 2; ++r) {
    int o = r * 4096 + tid * 16;
    int row = o >> 6;
    int ch = ((o >> 4) & 3) ^ (row & 3);
    int mrow = min(m0 + row, cnt - 1);
    srcA[r] = H + (size_t)(offe + mrow) * DF + ch * 8;
    srcB[r] = w2t + ((size_t)e * DM + n0 + row) * DF + ch * 8;
    ldso[r] = (unsigned)(r * 4096 + wv * 1024);
  }

  int fr = (wv >> 1) * 64 + (lane & 15);
  int fc = (wv & 1) * 64 + (lane & 15);
  int kqB = (lane >> 4) * 16;
  unsigned a_off[4], b_off[4];
  #pragma unroll
  for (int i = 0; i < 4; ++i) {
    int ra = fr + i * 16, rb = fc + i * 16;
    a_off[i] = (unsigned)((ra * 64 + kqB) ^ ((ra & 3) << 4));
    b_off[i] = (unsigned)(8192 + ((rb * 64 + kqB) ^ ((rb & 3) << 4)));
  }

  f32x4 acc[4][4];
  #pragma unroll
  for (int i = 0; i < 4; ++i)
    #pragma unroll
    for (int j = 0; j < 4; ++j)
      acc[i][j] = (f32x4){0.f, 0.f, 0.f, 0.f};

  for (int kt = 0; kt < DF / 32; ++kt) {
    #pragma unroll
    for (int r = 0; r < 2; ++r) {
      gload16(srcA[r] + kt * 32, smem + ldso[r]);
      gload16(srcB[r] + kt * 32, smem + 8192 + ldso[r]);
    }
    __syncthreads();
    bf16x8 af[4], bfr[4];
    #pragma unroll
    for (int i = 0; i < 4; ++i) af[i]  = *(const bf16x8*)(smem + a_off[i]);
    #pragma unroll
    for (int i = 0; i < 4; ++i) bfr[i] = *(const bf16x8*)(smem + b_off[i]);
    #pragma unroll
    for (int i = 0; i < 4; ++i)
      #pragma unroll
      for (int j = 0; j < 4; ++j)
        acc[i][j] = mfma_bf16(af[i], bfr[j], acc[i][j]);
    __syncthreads();
  }

  int rbase = (wv >> 1) * 64 + ((lane >> 4) << 2);
  int cbase = n0 + (wv & 1) * 64 + (lane & 15);
  #pragma unroll
  for (int i = 0; i < 4; ++i) {
    #pragma unroll
    for (int q = 0; q < 4; ++q) {
      int mg = m0 + rbase + i * 16 + q;
      if (mg < cnt) {
        int slot = offe + mg;
        int token = list[slot];
        float g = gl[slot];
        size_t orow = (size_t)token * DM;
        #pragma unroll
        for (int j = 0; j < 4; ++j) {
          int col = cbase + j * 16;
          float yv = acc[i][j][q] + b2[e * DM + col];
          atomicAdd(&out[orow + col], g * yv);
        }
      }
    }
  }
}

// ============================ launch ============================
extern "C" void kernel_launch(void* const* d_in, const int* in_sizes, int n_in,
                              void* d_out, int out_size, void* d_ws, size_t ws_size,
                              hipStream_t stream) {
  const float* x      = (const float*)d_in[0];
  const float* gate_w = (const float*)d_in[1];
  const float* ln_g   = (const float*)d_in[2];
  const float* ln_b   = (const float*)d_in[3];
  const float* w1     = (const float*)d_in[4];
  const float* b1     = (const float*)d_in[5];
  const float* w2     = (const float*)d_in[6];
  const float* b2     = (const float*)d_in[7];
  float* out = (float*)d_out;

  char* ws = (char*)d_ws;
  bf16_t* xn   = (bf16_t*)(ws);                                  // 16 MiB
  bf16_t* w1t  = (bf16_t*)(ws + 16777216ull);                    // 64 MiB  [E][F][D]
  bf16_t* w2t  = (bf16_t*)(ws + 83886080ull);                    // 64 MiB  [E][D][F]
  bf16_t* H    = (bf16_t*)(ws + 150994944ull);                   // 128 MiB [NP][F]
  int*    list = (int*)   (ws + 285212672ull);
  float*  gl   = (float*) (ws + 285278208ull);
  int*    eidx = (int*)   (ws + 285343744ull);
  float*  gts  = (float*) (ws + 285409280ull);
  int*    meta = (int*)   (ws + 285474816ull);

  hipMemsetAsync(meta, 0, 256, stream);
  k_router<<<T_TOK / 4, 256, 0, stream>>>(x, gate_w, ln_g, ln_b, out, xn, eidx, gts, meta);
  k_convT<<<dim3(DF / 32, DM / 32, NE), dim3(32, 8), 0, stream>>>(w1, w1t, DM, DF);
  k_convT<<<dim3(DM / 32, DF / 32, NE), dim3(32, 8), 0, stream>>>(w2, w2t, DF, DM);
  k_offsets<<<1, 1, 0, stream>>>(meta);
  k_assign<<<T_TOK / 256, 256, 0, stream>>>(eidx, gts, meta, list, gl);
  k_aux<<<1, 1, 0, stream>>>(meta, out + (size_t)T_TOK * DM);
  k_ffn1<<<dim3(DF / 128, 64, NE), 256, 0, stream>>>(xn, w1t, b1, H, list, meta);
  k_ffn2<<<dim3(DM / 128, 64, NE), 256, 0, stream>>>(H, w2t, b2, out, list, gl, meta);
}